// Round 13
// baseline (1525.754 us; speedup 1.0000x reference)
//
#include <hip/hip_runtime.h>

#define BB 32
#define TT 400
#define HH 512
#define NSTEP 100
#define VO 511
#define LSEQ 101
#define NBLK 256
#define NTHR 512
#define AOFF (BB*NSTEP*VO)
#define AXP 416
#define AG __HIP_MEMORY_SCOPE_AGENT
#define SPIN_CAP 20000000u

typedef float f4 __attribute__((ext_vector_type(4)));
typedef _Float16 v2h __attribute__((ext_vector_type(2)));
typedef _Float16 v8h __attribute__((ext_vector_type(8)));
typedef unsigned long long ull;

#if defined(__has_builtin)
#if __has_builtin(__builtin_amdgcn_fdot2)
#define HAVE_FDOT2 1
#endif
#endif
#ifdef HAVE_FDOT2
#define FDOT2(w, a, c) __builtin_amdgcn_fdot2((w), (a), (c), false)
#else
#define FDOT2(w, a, c) fmaf((float)(w)[0], (float)(a)[0], fmaf((float)(w)[1], (float)(a)[1], (c)))
#endif

#define DOT8(acc, wv, p0, p1, p2, p3)                      \
  acc = FDOT2((v2h{(wv)[0],(wv)[1]}), (p0), acc);          \
  acc = FDOT2((v2h{(wv)[2],(wv)[3]}), (p1), acc);          \
  acc = FDOT2((v2h{(wv)[4],(wv)[5]}), (p2), acc);          \
  acc = FDOT2((v2h{(wv)[6],(wv)[7]}), (p3), acc);

struct P {
  const float* x; const int* y; const float* emb;
  const float* wih; const float* whh; const float* bih; const float* bhh;
  const float* cw; const float* cb; const float* aw; const float* ab;
  const float* fw; const float* fb;
  float* out; int* ctrl; float* fws; _Float16* w16;
};

__device__ __forceinline__ float wredsum(float v) {
#pragma unroll
  for (int d = 1; d < 64; d <<= 1) v += __shfl_xor(v, d, 64);
  return v;
}
__device__ __forceinline__ float gld(const float* q) {
  return __hip_atomic_load(q, __ATOMIC_RELAXED, AG);
}
__device__ __forceinline__ void gst(float* q, float v) {
  __hip_atomic_store(q, v, __ATOMIC_RELAXED, AG);
}
__device__ __forceinline__ unsigned gldi(const int* q) {
  return __hip_atomic_load((const unsigned*)q, __ATOMIC_RELAXED, AG);
}
__device__ __forceinline__ void gsti(int* q, unsigned v) {
  __hip_atomic_store((unsigned*)q, v, __ATOMIC_RELAXED, AG);
}
__device__ __forceinline__ void gstll(ull* q, ull v) {
  __hip_atomic_store(q, v, __ATOMIC_RELAXED, AG);
}

__global__ __launch_bounds__(NTHR, 2) void seq2seq_kernel(P p) {
  const int tid  = threadIdx.x;
  const int lane = tid & 63;
  const int wave = tid >> 6;
  const int blk  = blockIdx.x;
  const int b   = blk >> 3;
  const int tch = blk & 7;
  const int t0  = tch * 50;
  const int hb  = tch * 64;
  const int h0s = lane * 8;

  // ---- LDS arena ----
  __shared__ __align__(16) char smem[64392];
  _Float16* xhL = (_Float16*)smem;                 // 51200
  float*    hxL = (float*)(smem + 51200);          // 2048
  _Float16* ixh = (_Float16*)(smem + 53248);       // 1024 (emb+sx; later Bh)
  _Float16* hxh = (_Float16*)(smem + 54272);       // 1024
  float*    redu= (float*)(smem + 55296);          // 8192: gi partials[0,1536) ∪ accS[0,1024); ghL[1536,1920)
  float*    accS= redu;
  float*    ghL = redu + 1536;                     // 384 floats: gh partials (w6: +0, w7: +192)
  float*    axs = (float*)(smem + 63488);          // 272
  v2h*      axp = (v2h*)(smem + 63760);            // 280
  float*    stL = (float*)(smem + 64040);          // 224
  float*    mS  = (float*)(smem + 64264);          // 32
  float*    lS  = mS + 8; float* pmL = mS + 16; float* plL = mS + 24;

  float* hx_rot = p.fws;                       // [2][BB][HH]
  float* ax_rot = hx_rot + 2*BB*HH;            // [2][BB][AXP]
  float* pm     = ax_rot + 2*BB*AXP;
  float* pl     = pm + 256;
  float* pacc   = pl + 256;                    // [BB][8][HH]
  const v8h* wiT = (const v8h*)p.w16;          // [3][64][512] ih (k-major)
  const v8h* whT = wiT + 98304;                // [3][64][512] hh
  const v8h* fwT = wiT + 196608;               // [64][512]    fc

  int* scf   = p.ctrl;
  int* hxf   = p.ctrl + 4096;
  int* initc = p.ctrl + 8192;
  int* scf_b = scf + b*128;
  int* hxf_b = hxf + b*128;

  auto wait8 = [&](int* base, unsigned target) {
    if (wave == 0) {
      unsigned it = 0;
      for (;;) {
        unsigned v = target;
        if (lane < 8) v = gldi(base + lane*16);
        if (__ballot(v < target) == 0ull) break;
        __builtin_amdgcn_s_sleep(1);
        if (++it > SPIN_CAP) break;
      }
    }
    __syncthreads();
  };

  // ---- persistent conv/attn weights ----
  v2h cwp[8][8]; float cbr[8], awr[8];
#pragma unroll
  for (int j = 0; j < 8; ++j) {
    int h = h0s + j;
    cbr[j] = p.cb[h]; awr[j] = p.aw[h];
#pragma unroll
    for (int mm = 0; mm < 8; ++mm) {
      float w0 = p.cw[h*15 + 2*mm];
      float w1 = (2*mm+1 < 15) ? p.cw[h*15 + 2*mm + 1] : 0.f;
      cwp[j][mm] = v2h{(_Float16)w0, (_Float16)w1};
    }
  }
  const float atb = p.ab[0];

  // ---- one-time: transposed fp16 weight build ----
  {
    const int gthr = NBLK*NTHR;
    const int gid = blk*NTHR + tid;
    auto cvt8 = [&](const float* s8, ull* dst) {
      v8h v;
#pragma unroll
      for (int e = 0; e < 8; ++e) v[e] = (_Float16)s8[e];
      union { v8h h; ull u[2]; } c; c.h = v;
      gstll(dst, c.u[0]); gstll(dst + 1, c.u[1]);
    };
    for (int i = gid; i < 98304; i += gthr) {
      int h = i & 511, kb = (i >> 9) & 63, g = i >> 15;
      cvt8(p.wih + ((size_t)(g*512 + h))*512 + kb*8, (ull*)((v8h*)p.w16 + i));
    }
    for (int i = gid; i < 98304; i += gthr) {
      int h = i & 511, kb = (i >> 9) & 63, g = i >> 15;
      cvt8(p.whh + ((size_t)(g*512 + h))*512 + kb*8, (ull*)((v8h*)p.w16 + 98304 + i));
    }
    for (int i = gid; i < 32768; i += gthr) {
      int h = i & 511, kb = i >> 9;
      ull* dst = (ull*)((v8h*)p.w16 + 196608 + i);
      if (h < VO) cvt8(p.fw + (size_t)h*512 + kb*8, dst);
      else { gstll(dst, 0ull); gstll(dst + 1, 0ull); }
    }
  }
  for (int i = 0; i < 50; ++i)
    xhL[i*512 + tid] = (_Float16)p.x[((size_t)b*TT + t0 + i)*HH + tid];
  hxL[tid] = 0.f;
  hxh[tid] = (_Float16)0.f;
  {
    const int yb = p.y[b*LSEQ + 0];
    ixh[tid] = (_Float16)p.emb[(size_t)yb*HH + tid];
  }
  if (tid < 384) ghL[tid] = 0.f;     // hx(−1)=0 -> gh = 0 exactly
  __syncthreads();
  if (tid == 0) {
    __builtin_amdgcn_s_waitcnt(0);
    __hip_atomic_fetch_add((unsigned*)initc, 1u, __ATOMIC_RELAXED, AG);
    unsigned it = 0;
    while (__hip_atomic_load((unsigned*)initc, __ATOMIC_RELAXED, AG) < (unsigned)NBLK) {
      __builtin_amdgcn_s_sleep(2);
      if (++it > SPIN_CAP) break;
    }
  }
  __syncthreads();

  // ---- gi phase: W_ih·ixh partials + ghL merge -> hx(s+1); publish hxf=s+2 ----
  auto gi_phase = [&](int s) {
    const int hg = hb + lane;
    const v2h* ixp = (const v2h*)ixh;
    float g0 = 0.f, g1 = 0.f, g2 = 0.f;
#pragma unroll 2
    for (int kb = 0; kb < 8; ++kb) {
      const int kbg = wave*8 + kb;
      const int pb  = kbg*4;
      v2h a0 = ixp[pb], a1 = ixp[pb+1], a2 = ixp[pb+2], a3 = ixp[pb+3];
      v8h w0 = wiT[(0*64 + kbg)*512 + hg];
      v8h w1 = wiT[(1*64 + kbg)*512 + hg];
      v8h w2 = wiT[(2*64 + kbg)*512 + hg];
      DOT8(g0, w0, a0, a1, a2, a3);
      DOT8(g1, w1, a0, a1, a2, a3);
      DOT8(g2, w2, a0, a1, a2, a3);
    }
    redu[wave*192 +   0 + lane] = g0;
    redu[wave*192 +  64 + lane] = g1;
    redu[wave*192 + 128 + lane] = g2;
    __syncthreads();
    if (tid < 192) {
      float v = 0.f;
#pragma unroll
      for (int w = 0; w < 8; ++w) v += redu[w*192 + tid];
      redu[tid] = v;
    }
    __syncthreads();
    if (tid < 64) {
      const int hh_ = hb + tid;
      float ghr = ghL[tid]       + ghL[192 + tid];
      float ghz = ghL[64 + tid]  + ghL[256 + tid];
      float ghn = ghL[128 + tid] + ghL[320 + tid];
      float rg = 1.f/(1.f + __expf(-(redu[tid] + ghr + p.bih[hh_] + p.bhh[hh_])));
      float zg = 1.f/(1.f + __expf(-(redu[64+tid] + ghz + p.bih[512+hh_] + p.bhh[512+hh_])));
      float na = (redu[128+tid] + p.bih[1024+hh_]) + rg*(ghn + p.bhh[1024+hh_]);
      float e2 = __expf(2.f*na);
      float nn = 1.f - 2.f/(e2 + 1.f);
      float hnew = (1.f - zg)*nn + zg*hxL[hh_];
      float* hx_n = hx_rot + (size_t)((unsigned)(s+1) & 1)*BB*HH + (size_t)b*HH;
      gst(hx_n + hh_, hnew);
    }
    __syncthreads();
    if (tid == 0) gsti(hxf_b + tch*16, (unsigned)(s+2));
  };

  gi_phase(-1);     // hx(0); ghL zeroed above

  for (int s = 0; s < NSTEP; ++s) {
    const int par = s & 1;
    // ---- gate A: hx(s) ready ----
    wait8(hxf_b, (unsigned)(s+1));
    {
      float hv = gld(hx_rot + (size_t)par*BB*HH + (size_t)b*HH + tid);
      if (s > 0 && tid < 68) {
        int tg = t0 - 8 + tid;
        axs[tid] = (tg >= 0 && tg < TT)
                 ? gld(ax_rot + (size_t)((s-1)&1)*BB*AXP + (size_t)b*AXP + tg) : 0.f;
      }
      hxL[tid] = hv;
      hxh[tid] = (_Float16)hv;
    }
    __syncthreads();
    if (s > 0) {
      if (tid < 34) axp[tid] = v2h{(_Float16)axs[2*tid], (_Float16)axs[2*tid+1]};
      else if (tid >= 64 && tid < 98) {
        int mm = tid - 64;
        float a1 = (2*mm+2 < 68) ? axs[2*mm+2] : 0.f;
        axp[34+mm] = v2h{(_Float16)axs[2*mm+1], (_Float16)a1};
      }
      __syncthreads();
    }
    // ==== FORK: waves 0-5 score; waves 6-7 stream gh = W_hh·hx(s) ====
    float m = -1e30f, l = 0.f, acc[8];
#pragma unroll
    for (int j = 0; j < 8; ++j) acc[j] = 0.f;
    if (wave < 6) {
      float hxr[8];
#pragma unroll
      for (int j = 0; j < 8; ++j) hxr[j] = hxL[h0s + j];
#pragma unroll 2
      for (int it = 0; it < 9; ++it) {
        const int lt = wave + it*6;
        if (lt < 50) {
          v8h xv = *(const v8h*)(xhL + lt*512 + h0s);
          float xr[8];
#pragma unroll
          for (int j = 0; j < 8; ++j) xr[j] = (float)xv[j];
          float cc[8];
          if (s > 0) {
            const int li0 = lt + 1;
            const v2h* ap2 = axp + ((li0 & 1) ? (34 + ((li0-1) >> 1)) : (li0 >> 1));
            v2h av2[8];
#pragma unroll
            for (int mm = 0; mm < 8; ++mm) av2[mm] = ap2[mm];
#pragma unroll
            for (int j = 0; j < 8; ++j) {
              float a = cbr[j];
#pragma unroll
              for (int mm = 0; mm < 8; ++mm) a = FDOT2(cwp[j][mm], av2[mm], a);
              cc[j] = a;
            }
          } else {
#pragma unroll
            for (int j = 0; j < 8; ++j) cc[j] = 0.f;
          }
          float part = 0.f;
#pragma unroll
          for (int j = 0; j < 8; ++j) {
            float vv = xr[j] + hxr[j] + cc[j];
            vv = fmaxf(vv, 0.f);
            part = fmaf(vv, awr[j], part);
          }
          part = wredsum(part);
          float st = part + atb;
          if (lane == 0) stL[lt] = st;
          float mn  = fmaxf(m, st);
          float scl = __expf(m - mn);
          float pe  = __expf(st - mn);
          l = l*scl + pe;
#pragma unroll
          for (int j = 0; j < 8; ++j) acc[j] = fmaf(acc[j], scl, pe*xr[j]);
          m = mn;
        }
      }
    } else {
      // gh streaming: wave 6 -> kb 0..31, wave 7 -> kb 32..63
      const int wq = wave - 6;
      const int hg = hb + lane;
      const v2h* hxp = (const v2h*)hxh;
      float p0 = 0.f, p1 = 0.f, p2 = 0.f;
#pragma unroll 2
      for (int i = 0; i < 32; ++i) {
        const int kbg = wq*32 + i;
        const int pb  = kbg*4;
        v2h c0 = hxp[pb], c1 = hxp[pb+1], c2 = hxp[pb+2], c3 = hxp[pb+3];
        v8h w0 = whT[(0*64 + kbg)*512 + hg];
        v8h w1 = whT[(1*64 + kbg)*512 + hg];
        v8h w2 = whT[(2*64 + kbg)*512 + hg];
        DOT8(p0, w0, c0, c1, c2, c3);
        DOT8(p1, w1, c0, c1, c2, c3);
        DOT8(p2, w2, c0, c1, c2, c3);
      }
      ghL[wq*192 +   0 + lane] = p0;
      ghL[wq*192 +  64 + lane] = p1;
      ghL[wq*192 + 128 + lane] = p2;
    }
    __syncthreads();   // rejoin
    if (wave < 6 && lane == 0) { mS[wave] = m; lS[wave] = l; }
    __syncthreads();
    float mb = mS[0];
#pragma unroll
    for (int w = 1; w < 6; ++w) mb = fmaxf(mb, mS[w]);
    float lb = 0.f, ew[6];
#pragma unroll
    for (int w = 0; w < 6; ++w) { ew[w] = __expf(mS[w] - mb); lb = fmaf(ew[w], lS[w], lb); }
    // 3-phase merge of 6 wave-accumulators into 2-slot accS (all waves hit barriers)
#pragma unroll
    for (int ph = 0; ph < 3; ++ph) {
      if ((wave >> 1) == ph) {
        float* dst = accS + (wave & 1)*512 + h0s;
        if (ph == 0) {
#pragma unroll
          for (int j = 0; j < 8; ++j) dst[j] = ew[wave]*acc[j];
        } else {
#pragma unroll
          for (int j = 0; j < 8; ++j) dst[j] += ew[wave]*acc[j];
        }
      }
      __syncthreads();
    }
    float ab = accS[tid] + accS[512 + tid];
    gst(&pacc[(size_t)(b*8 + tch)*HH + tid], ab);
    if (tid == 0) { gst(&pm[b*8+tch], mb); gst(&pl[b*8+tch], lb); }
    __syncthreads();
    if (tid == 0) gsti(scf_b + tch*16, (unsigned)(s+1));
    float embr = 0.f;
    if (s < NSTEP-1)
      embr = p.emb[(size_t)p.y[b*LSEQ + (s+1)]*HH + tid];
    wait8(scf_b, (unsigned)(s+1));
    // ---- combine ----
    if (tid < 8)       pmL[tid]   = gld(&pm[b*8 + tid]);
    else if (tid < 16) plL[tid-8] = gld(&pl[b*8 + tid - 8]);
    __syncthreads();
    float mm2 = pmL[0];
#pragma unroll
    for (int c = 1; c < 8; ++c) mm2 = fmaxf(mm2, pmL[c]);
    float ls = 0.f, ee[8];
#pragma unroll
    for (int c = 0; c < 8; ++c) { ee[c] = __expf(pmL[c] - mm2); ls = fmaf(ee[c], plL[c], ls); }
    float inv = 1.f / ls;
    float sv = 0.f;
#pragma unroll
    for (int c = 0; c < 8; ++c) {
      float pv = (c == tch) ? ab : gld(&pacc[(size_t)(b*8+c)*HH + tid]);
      sv = fmaf(ee[c], pv, sv);
    }
    const float sxv = sv * inv;
    if (tid < 50) {
      float a = __expf(stL[tid] - mm2) * inv;
      gst(ax_rot + (size_t)par*BB*AXP + (size_t)b*AXP + t0 + tid, a);
      p.out[AOFF + (size_t)b*NSTEP*TT + (size_t)s*TT + t0 + tid] = a;
    }
    if (s < NSTEP-1) ixh[tid] = (_Float16)(embr + sxv);
    __syncthreads();
    // ---- gi-only GRU (gh already in LDS) ----
    if (s < NSTEP-1) gi_phase(s);
    // ---- FC (off critical path): Bh reuses ixh ----
    ixh[tid] = (_Float16)(hxL[tid] + sxv);
    __syncthreads();
    {
      const int rowg = hb + lane;
      const v2h* bp = (const v2h*)ixh;
      float pf = 0.f;
#pragma unroll 2
      for (int kb = 0; kb < 8; ++kb) {
        const int kbg = wave*8 + kb;
        const int pb  = kbg*4;
        v8h w = fwT[kbg*512 + rowg];
        DOT8(pf, w, bp[pb], bp[pb+1], bp[pb+2], bp[pb+3]);
      }
      redu[wave*64 + lane] = pf;
      __syncthreads();
      if (tid < 64) {
        float v = 0.f;
#pragma unroll
        for (int w = 0; w < 8; ++w) v += redu[w*64 + tid];
        const int r2 = hb + tid;
        if (r2 < VO)
          p.out[(size_t)b*NSTEP*VO + (size_t)s*VO + r2] = v + p.fb[r2];
      }
      __syncthreads();   // protect redu before next step's use
    }
  }
}

extern "C" void kernel_launch(void* const* d_in, const int* in_sizes, int n_in,
                              void* d_out, int out_size, void* d_ws, size_t ws_size,
                              hipStream_t stream) {
  P p;
  p.x   = (const float*)d_in[0];
  p.y   = (const int*)  d_in[1];
  p.emb = (const float*)d_in[2];
  p.wih = (const float*)d_in[3];
  p.whh = (const float*)d_in[4];
  p.bih = (const float*)d_in[5];
  p.bhh = (const float*)d_in[6];
  p.cw  = (const float*)d_in[7];
  p.cb  = (const float*)d_in[8];
  p.aw  = (const float*)d_in[9];
  p.ab  = (const float*)d_in[10];
  p.fw  = (const float*)d_in[11];
  p.fb  = (const float*)d_in[12];
  p.out = (float*)d_out;
  p.ctrl = (int*)d_ws;
  size_t flcount = (size_t)2*BB*HH + (size_t)2*BB*AXP + 512 + (size_t)BB*8*HH;
  p.fws = (float*)((char*)d_ws + 49152);
  p.w16 = (_Float16*)((char*)d_ws + 49152 + 4*flcount);

  hipMemsetAsync(d_ws, 0, 49152, stream);

  void* args[] = { &p };
  hipError_t err = hipLaunchCooperativeKernel((const void*)seq2seq_kernel,
                                              dim3(NBLK), dim3(NTHR), args, 0, stream);
  if (err != hipSuccess) {
    seq2seq_kernel<<<dim3(NBLK), dim3(NTHR), 0, stream>>>(p);
  }
}